// Round 10
// baseline (95.829 us; speedup 1.0000x reference)
//
#include <hip/hip_runtime.h>
#include <hip/hip_bf16.h>

// RBF collocation, N=6144, 17 outputs (closed-form nested JVPs of Gaussian RBF).
// MFMA factorization (validated R5-R9): out = linear-epilogue( W = G @ V ),
//   G[i,j] = exp(-0.5*||c_j - p_i||^2)  (bf16 A-fragments computed in-lane),
//   V [N x 21] = {v1,cx*v1,cz*v1 | v_k,cx*v_k,cz*v_k,ct*v_k,cx^2*v_k,cz^2*v_k}.
// R10: R9 structure frozen; SPLIT 16->32 (grid 3072, KC=192, NSTEP=6) to raise
// resident waves 6->8 blocks/CU + block churn (12 blocks/CU total) — attacks
// the latency-bound gap (issue model ~7us vs measured ~27us for main3).
// Dtypes proven R1-R3: inputs fp32, output fp32. Harness floor ~62-65us.

#define NPTS 6144
#define NOUTS (17 * NPTS)
#define SPLIT 32
#define KC (NPTS / SPLIT)     // 192 j per block
#define NSTEP (KC / 32)       // 6 MFMA K-steps
#define VROW 204              // LDS V row stride (bf16); word-stride 102 ≡ 6 mod 32
#define SCALE 0.8493218002880191f   // sqrt(log2(e)/2); dx'^2 = 0.72134*dx^2

typedef float  f32x4  __attribute__((ext_vector_type(4)));
typedef __bf16 bf16x8 __attribute__((ext_vector_type(8)));

#if defined(__has_builtin) && __has_builtin(__builtin_amdgcn_exp2f)
#define EXP2F(x) __builtin_amdgcn_exp2f(x)
#else
#define EXP2F(x) __expf((x) * 0.6931471805599453f)
#endif

// V-column order: 0:v1 1:cx*v1 2:cz*v1 | 3..8: v2 {1,cx,cz,ct,cx2,cz2}
// | 9..14: v3 same | 15..20: v4 same
__global__ void rbf_prep(const float* __restrict__ cp,
                         const float* __restrict__ v1p,
                         const float* __restrict__ v2p,
                         const float* __restrict__ v3p,
                         const float* __restrict__ v4p,
                         float* __restrict__ cxa, float* __restrict__ cza,
                         float* __restrict__ cta, __bf16* __restrict__ vt,
                         float* __restrict__ out) {
  const int j = blockIdx.x * blockDim.x + threadIdx.x;
  // zero d_out (poisoned 0xAA each call; main accumulates atomically)
  for (int i = j; i < NOUTS; i += NPTS) out[i] = 0.f;
  const float cx = cp[3 * j], cz = cp[3 * j + 1], ct = cp[3 * j + 2];
  cxa[j] = cx * SCALE; cza[j] = cz * SCALE; cta[j] = ct * SCALE;
  const float a1 = v1p[j];
  vt[0 * NPTS + j] = (__bf16)a1;
  vt[1 * NPTS + j] = (__bf16)(cx * a1);
  vt[2 * NPTS + j] = (__bf16)(cz * a1);
#pragma unroll
  for (int k = 0; k < 3; ++k) {         // v2, v3, v4
    const float v = (k == 0) ? v2p[j] : (k == 1) ? v3p[j] : v4p[j];
    const int r = 3 + 6 * k;
    vt[(r + 0) * NPTS + j] = (__bf16)v;
    vt[(r + 1) * NPTS + j] = (__bf16)(cx * v);
    vt[(r + 2) * NPTS + j] = (__bf16)(cz * v);
    vt[(r + 3) * NPTS + j] = (__bf16)(ct * v);
    vt[(r + 4) * NPTS + j] = (__bf16)(cx * cx * v);
    vt[(r + 5) * NPTS + j] = (__bf16)(cz * cz * v);
  }
}

__global__ __launch_bounds__(256) void rbf_main3(
    const float* __restrict__ xp, const float* __restrict__ zp,
    const float* __restrict__ tp,
    const float* __restrict__ cxa, const float* __restrict__ cza,
    const float* __restrict__ cta,
    const __bf16* __restrict__ vt,
    float* __restrict__ out) {
  __shared__ __align__(16) unsigned char smem[21 * VROW * 2];  // 8568 B
  __bf16 (*vlds)[VROW] = reinterpret_cast<__bf16(*)[VROW]>(smem);

  const int rg = blockIdx.x % 96;       // row-group (64 rows)
  const int s  = blockIdx.x / 96;       // K-split 0..31
  const int w    = threadIdx.x >> 6;
  const int lane = threadIdx.x & 63;
  const int lo   = lane & 15;           // A row / D col / B col
  const int hi   = lane >> 4;           // k-group: lane holds k = hi*8 + i
  const int lo5  = lo % 5;              // vb1 row (acc1 cols >=5 discarded)

  // ---- stage Vt[21][KC] slice into LDS, coalesced 16B chunks ----
  {
    const __bf16* src = vt + s * KC;
#pragma unroll
    for (int it = 0; it < 2; ++it) {    // 21 rows * 24 chunks = 504 / 256
      const int idx = threadIdx.x + it * 256;
      if (idx < 21 * 24) {
        const int c = idx / 24, ch = idx % 24;
        *(bf16x8*)&vlds[c][ch * 8] =
            *(const bf16x8*)(src + (size_t)c * NPTS + ch * 8);
      }
    }
  }
  __syncthreads();

  const int rowbase = rg * 64 + w * 16;
  const int row = rowbase + lo;
  const float xs = xp[row] * SCALE, zs = zp[row] * SCALE, ts = tp[row] * SCALE;

  const float* __restrict__ cxg = cxa + s * KC;
  const float* __restrict__ czg = cza + s * KC;
  const float* __restrict__ ctg = cta + s * KC;

  f32x4 acc0 = {0.f, 0.f, 0.f, 0.f};
  f32x4 acc1 = {0.f, 0.f, 0.f, 0.f};

#pragma unroll 2
  for (int step = 0; step < NSTEP; ++step) {
    const int kb = hi * 8 + step * 32;
    const f32x4 cx0 = *(const f32x4*)(cxg + kb);
    const f32x4 cx1 = *(const f32x4*)(cxg + kb + 4);
    const f32x4 cz0 = *(const f32x4*)(czg + kb);
    const f32x4 cz1 = *(const f32x4*)(czg + kb + 4);
    const f32x4 ct0 = *(const f32x4*)(ctg + kb);
    const f32x4 ct1 = *(const f32x4*)(ctg + kb + 4);
    const bf16x8 b0 = *(const bf16x8*)&vlds[lo][kb];         // cols 0..15
    const bf16x8 b1 = *(const bf16x8*)&vlds[16 + lo5][kb];   // cols 16..20

    bf16x8 af;
#pragma unroll
    for (int i = 0; i < 4; ++i) {
      const float dx = cx0[i] - xs, dz = cz0[i] - zs, dt = ct0[i] - ts;
      const float r2 = fmaf(dx, dx, fmaf(dz, dz, dt * dt));  // pre-scaled
      af[i] = (__bf16)EXP2F(-r2);                            // = exp(-0.5*r2)
    }
#pragma unroll
    for (int i = 0; i < 4; ++i) {
      const float dx = cx1[i] - xs, dz = cz1[i] - zs, dt = ct1[i] - ts;
      const float r2 = fmaf(dx, dx, fmaf(dz, dz, dt * dt));
      af[4 + i] = (__bf16)EXP2F(-r2);
    }
    acc0 = __builtin_amdgcn_mfma_f32_16x16x32_bf16(af, b0, acc0, 0, 0, 0);
    acc1 = __builtin_amdgcn_mfma_f32_16x16x32_bf16(af, b1, acc1, 0, 0, 0);
  }

  // ---- W tile -> LDS (reuse staging area), then per-row atomic epilogue ----
  __syncthreads();                       // all waves done reading vlds
  float* redw = reinterpret_cast<float*>(smem) + w * (16 * 33);
  // D layout: col = lane&15, row = (lane>>4)*4 + reg  [m89-verified]
#pragma unroll
  for (int reg = 0; reg < 4; ++reg) {
    const int r = hi * 4 + reg;
    redw[r * 33 + lo]      = acc0[reg];
    redw[r * 33 + lo + 16] = acc1[reg];
  }
  __syncthreads();

  if (lane < 16) {
    const int orow = rowbase + lane;
    float wv[21];
#pragma unroll
    for (int c = 0; c < 21; ++c) wv[c] = redw[lane * 33 + c];
    const float x = xp[orow], z = zp[orow], t = tp[orow];
    const float x2 = fmaf(x, x, -1.f), z2 = fmaf(z, z, -1.f);
    float* o = out;
    atomicAdd(&o[0 * NPTS + orow],  wv[10] - x * wv[9]);                     // dudx
    atomicAdd(&o[1 * NPTS + orow],  wv[11] - z * wv[9]);                     // dudz
    atomicAdd(&o[2 * NPTS + orow],  wv[12] - t * wv[9]);                     // dudt
    atomicAdd(&o[3 * NPTS + orow],  wv[16] - x * wv[15]);                    // dwdx
    atomicAdd(&o[4 * NPTS + orow],  wv[17] - z * wv[15]);                    // dwdz
    atomicAdd(&o[5 * NPTS + orow],  wv[18] - t * wv[15]);                    // dwdt
    atomicAdd(&o[6 * NPTS + orow],  wv[4]  - x * wv[3]);                     // dbdx
    atomicAdd(&o[7 * NPTS + orow],  wv[5]  - z * wv[3]);                     // dbdz
    atomicAdd(&o[8 * NPTS + orow],  wv[6]  - t * wv[3]);                     // dbdt
    atomicAdd(&o[9 * NPTS + orow],  wv[1]  - x * wv[0]);                     // dpdx
    atomicAdd(&o[10 * NPTS + orow], wv[2]  - z * wv[0]);                     // dpdz
    atomicAdd(&o[11 * NPTS + orow], wv[13] - 2.f * x * wv[10] + x2 * wv[9]); // d2u2x
    atomicAdd(&o[12 * NPTS + orow], wv[14] - 2.f * z * wv[11] + z2 * wv[9]); // d2u2z
    atomicAdd(&o[13 * NPTS + orow], wv[19] - 2.f * x * wv[16] + x2 * wv[15]);// d2w2x
    atomicAdd(&o[14 * NPTS + orow], wv[20] - 2.f * z * wv[17] + z2 * wv[15]);// d2w2z
    atomicAdd(&o[15 * NPTS + orow], wv[7]  - 2.f * x * wv[4]  + x2 * wv[3]); // d2b2x
    atomicAdd(&o[16 * NPTS + orow], wv[8]  - 2.f * z * wv[5]  + z2 * wv[3]); // d2b2z
  }
}

extern "C" void kernel_launch(void* const* d_in, const int* in_sizes, int n_in,
                              void* d_out, int out_size, void* d_ws, size_t ws_size,
                              hipStream_t stream) {
  const float* xp  = (const float*)d_in[0];
  const float* zp  = (const float*)d_in[1];
  const float* tp  = (const float*)d_in[2];
  const float* cp  = (const float*)d_in[3];
  const float* v1p = (const float*)d_in[4];
  const float* v2p = (const float*)d_in[5];
  const float* v3p = (const float*)d_in[6];
  const float* v4p = (const float*)d_in[7];

  float* ws  = (float*)d_ws;
  float* cxa = ws;
  float* cza = ws + NPTS;
  float* cta = ws + 2 * NPTS;
  __bf16* vt = (__bf16*)(ws + 3 * NPTS);

  rbf_prep<<<NPTS / 256, 256, 0, stream>>>(cp, v1p, v2p, v3p, v4p,
                                           cxa, cza, cta, vt, (float*)d_out);

  rbf_main3<<<96 * SPLIT, 256, 0, stream>>>(xp, zp, tp, cxa, cza, cta, vt,
                                            (float*)d_out);
}

// Round 11
// 83.111 us; speedup vs baseline: 1.1530x; 1.1530x over previous
//
#include <hip/hip_runtime.h>
#include <hip/hip_bf16.h>

// RBF collocation, N=6144, 17 outputs (closed-form nested JVPs of Gaussian RBF).
// MFMA factorization (validated R5-R10): out = linear-epilogue( W = G @ V ),
//   G[i,j] = exp(-0.5*||c_j - p_i||^2)  (bf16 A-fragments computed in-lane),
//   V [N x 21] = {v1,cx*v1,cz*v1 | v_k,cx*v_k,cz*v_k,ct*v_k,cx^2*v_k,cz^2*v_k}.
// R11: SINGLE kernel. R9's K-loop/epilogue frozen (SPLIT=16, atomics, no
// min-wave launch_bounds); prep fused as in-block LDS staging from raw inputs
// (no ws use at all); d_out zeroed via hipMemsetAsync graph node.
// Disambiguates R8's confounds (launch_bounds spill vs staging cost) and
// removes prep launch + gap. Dtypes proven R1-R3: inputs fp32, output fp32.

#define NPTS 6144
#define SPLIT 16
#define KC (NPTS / SPLIT)     // 384 j per block
#define NSTEP (KC / 32)       // 12 MFMA K-steps
#define VROW 392              // LDS V row stride in bf16 (784 B, 16B-aligned)
#define SCALE 0.8493218002880191f   // sqrt(log2(e)/2); dx'^2 = 0.72134*dx^2

typedef float  f32x4  __attribute__((ext_vector_type(4)));
typedef __bf16 bf16x8 __attribute__((ext_vector_type(8)));

#if defined(__has_builtin) && __has_builtin(__builtin_amdgcn_exp2f)
#define EXP2F(x) __builtin_amdgcn_exp2f(x)
#else
#define EXP2F(x) __expf((x) * 0.6931471805599453f)
#endif

// V-column order: 0:v1 1:cx*v1 2:cz*v1 | 3..8: v2 {1,cx,cz,ct,cx2,cz2}
// | 9..14: v3 same | 15..20: v4 same
__global__ __launch_bounds__(256) void rbf_fused(
    const float* __restrict__ xp, const float* __restrict__ zp,
    const float* __restrict__ tp, const float* __restrict__ cp,
    const float* __restrict__ v1p, const float* __restrict__ v2p,
    const float* __restrict__ v3p, const float* __restrict__ v4p,
    float* __restrict__ out) {
  __shared__ __align__(16) float  cs[3][KC];       // scaled c slice, 4608 B
  __shared__ __align__(16) __bf16 vlds[21][VROW];  // V slice, 16464 B

  const int rg = blockIdx.x % 96;       // row-group (64 rows)
  const int s  = blockIdx.x / 96;       // K-split 0..15

  // ---- in-block staging from raw inputs (fused prep) ----
  for (int j = threadIdx.x; j < KC; j += 256) {
    const int jg = s * KC + j;
    const float cx = cp[3 * jg], cz = cp[3 * jg + 1], ct = cp[3 * jg + 2];
    cs[0][j] = cx * SCALE; cs[1][j] = cz * SCALE; cs[2][j] = ct * SCALE;
    const float a1 = v1p[jg];
    vlds[0][j] = (__bf16)a1;
    vlds[1][j] = (__bf16)(cx * a1);
    vlds[2][j] = (__bf16)(cz * a1);
    const float vs[3] = {v2p[jg], v3p[jg], v4p[jg]};
#pragma unroll
    for (int k2 = 0; k2 < 3; ++k2) {
      const float v = vs[k2];
      const int r = 3 + 6 * k2;
      vlds[r + 0][j] = (__bf16)v;
      vlds[r + 1][j] = (__bf16)(cx * v);
      vlds[r + 2][j] = (__bf16)(cz * v);
      vlds[r + 3][j] = (__bf16)(ct * v);
      vlds[r + 4][j] = (__bf16)(cx * cx * v);
      vlds[r + 5][j] = (__bf16)(cz * cz * v);
    }
  }
  __syncthreads();

  const int w    = threadIdx.x >> 6;
  const int lane = threadIdx.x & 63;
  const int lo   = lane & 15;           // A row / D col / B col
  const int hi   = lane >> 4;           // k-group: lane holds k = hi*8 + i
  const int lo5  = lo % 5;              // vb1 row (acc1 cols >=5 discarded)

  const int rowbase = rg * 64 + w * 16;
  const int row = rowbase + lo;
  const float xs = xp[row] * SCALE, zs = zp[row] * SCALE, ts = tp[row] * SCALE;

  f32x4 acc0 = {0.f, 0.f, 0.f, 0.f};
  f32x4 acc1 = {0.f, 0.f, 0.f, 0.f};

#pragma unroll 2
  for (int step = 0; step < NSTEP; ++step) {
    const int kb = hi * 8 + step * 32;
    const f32x4 cx0 = *(const f32x4*)&cs[0][kb];
    const f32x4 cx1 = *(const f32x4*)&cs[0][kb + 4];
    const f32x4 cz0 = *(const f32x4*)&cs[1][kb];
    const f32x4 cz1 = *(const f32x4*)&cs[1][kb + 4];
    const f32x4 ct0 = *(const f32x4*)&cs[2][kb];
    const f32x4 ct1 = *(const f32x4*)&cs[2][kb + 4];
    const bf16x8 b0 = *(const bf16x8*)&vlds[lo][kb];         // cols 0..15
    const bf16x8 b1 = *(const bf16x8*)&vlds[16 + lo5][kb];   // cols 16..20

    bf16x8 af;
#pragma unroll
    for (int i = 0; i < 4; ++i) {
      const float dx = cx0[i] - xs, dz = cz0[i] - zs, dt = ct0[i] - ts;
      const float r2 = fmaf(dx, dx, fmaf(dz, dz, dt * dt));  // pre-scaled
      af[i] = (__bf16)EXP2F(-r2);                            // = exp(-0.5*r2)
    }
#pragma unroll
    for (int i = 0; i < 4; ++i) {
      const float dx = cx1[i] - xs, dz = cz1[i] - zs, dt = ct1[i] - ts;
      const float r2 = fmaf(dx, dx, fmaf(dz, dz, dt * dt));
      af[4 + i] = (__bf16)EXP2F(-r2);
    }
    acc0 = __builtin_amdgcn_mfma_f32_16x16x32_bf16(af, b0, acc0, 0, 0, 0);
    acc1 = __builtin_amdgcn_mfma_f32_16x16x32_bf16(af, b1, acc1, 0, 0, 0);
  }

  // ---- W tile -> LDS (reuse staging area), then per-row atomic epilogue ----
  __syncthreads();                       // all waves done reading vlds
  float* redw = reinterpret_cast<float*>(vlds) + w * (16 * 33);
  // D layout: col = lane&15, row = (lane>>4)*4 + reg  [m89-verified]
#pragma unroll
  for (int reg = 0; reg < 4; ++reg) {
    const int r = hi * 4 + reg;
    redw[r * 33 + lo]      = acc0[reg];
    redw[r * 33 + lo + 16] = acc1[reg];
  }
  __syncthreads();

  if (lane < 16) {
    const int orow = rowbase + lane;
    float wv[21];
#pragma unroll
    for (int c = 0; c < 21; ++c) wv[c] = redw[lane * 33 + c];
    const float x = xp[orow], z = zp[orow], t = tp[orow];
    const float x2 = fmaf(x, x, -1.f), z2 = fmaf(z, z, -1.f);
    float* o = out;
    atomicAdd(&o[0 * NPTS + orow],  wv[10] - x * wv[9]);                     // dudx
    atomicAdd(&o[1 * NPTS + orow],  wv[11] - z * wv[9]);                     // dudz
    atomicAdd(&o[2 * NPTS + orow],  wv[12] - t * wv[9]);                     // dudt
    atomicAdd(&o[3 * NPTS + orow],  wv[16] - x * wv[15]);                    // dwdx
    atomicAdd(&o[4 * NPTS + orow],  wv[17] - z * wv[15]);                    // dwdz
    atomicAdd(&o[5 * NPTS + orow],  wv[18] - t * wv[15]);                    // dwdt
    atomicAdd(&o[6 * NPTS + orow],  wv[4]  - x * wv[3]);                     // dbdx
    atomicAdd(&o[7 * NPTS + orow],  wv[5]  - z * wv[3]);                     // dbdz
    atomicAdd(&o[8 * NPTS + orow],  wv[6]  - t * wv[3]);                     // dbdt
    atomicAdd(&o[9 * NPTS + orow],  wv[1]  - x * wv[0]);                     // dpdx
    atomicAdd(&o[10 * NPTS + orow], wv[2]  - z * wv[0]);                     // dpdz
    atomicAdd(&o[11 * NPTS + orow], wv[13] - 2.f * x * wv[10] + x2 * wv[9]); // d2u2x
    atomicAdd(&o[12 * NPTS + orow], wv[14] - 2.f * z * wv[11] + z2 * wv[9]); // d2u2z
    atomicAdd(&o[13 * NPTS + orow], wv[19] - 2.f * x * wv[16] + x2 * wv[15]);// d2w2x
    atomicAdd(&o[14 * NPTS + orow], wv[20] - 2.f * z * wv[17] + z2 * wv[15]);// d2w2z
    atomicAdd(&o[15 * NPTS + orow], wv[7]  - 2.f * x * wv[4]  + x2 * wv[3]); // d2b2x
    atomicAdd(&o[16 * NPTS + orow], wv[8]  - 2.f * z * wv[5]  + z2 * wv[3]); // d2b2z
  }
}

extern "C" void kernel_launch(void* const* d_in, const int* in_sizes, int n_in,
                              void* d_out, int out_size, void* d_ws, size_t ws_size,
                              hipStream_t stream) {
  const float* xp  = (const float*)d_in[0];
  const float* zp  = (const float*)d_in[1];
  const float* tp  = (const float*)d_in[2];
  const float* cp  = (const float*)d_in[3];
  const float* v1p = (const float*)d_in[4];
  const float* v2p = (const float*)d_in[5];
  const float* v3p = (const float*)d_in[6];
  const float* v4p = (const float*)d_in[7];

  // zero d_out (poisoned 0xAA each call; kernel accumulates atomically).
  // Memset nodes are graph-capture legal (harness itself uses hipMemsetAsync).
  hipMemsetAsync(d_out, 0, (size_t)out_size * sizeof(float), stream);

  rbf_fused<<<96 * SPLIT, 256, 0, stream>>>(xp, zp, tp, cp,
                                            v1p, v2p, v3p, v4p, (float*)d_out);
}

// Round 12
// 80.914 us; speedup vs baseline: 1.1843x; 1.0272x over previous
//
#include <hip/hip_runtime.h>
#include <hip/hip_bf16.h>

// RBF collocation, N=6144, 17 outputs (closed-form nested JVPs of Gaussian RBF).
// MFMA factorization (validated R5-R11): out = linear-epilogue( W = G @ V ),
//   G[i,j] = exp(-0.5*||c_j - p_i||^2)  (bf16 A-fragments computed in-lane),
//   V [N x 21] = {v1,cx*v1,cz*v1 | v_k,cx*v_k,cz*v_k,ct*v_k,cx^2*v_k,cz^2*v_k}.
// R12: R11 frozen (single fused kernel, SPLIT=16, atomic epilogue, memset node)
// + distance chain in packed fp32 (float2 -> v_pk_fma_f32): 48->24 VALU/step.
// Attribution probe: no delta => K-loop latency-bound, ~83us is the plateau.
// Dtypes proven R1-R3: inputs fp32, output fp32. Harness floor ~64us.

#define NPTS 6144
#define SPLIT 16
#define KC (NPTS / SPLIT)     // 384 j per block
#define NSTEP (KC / 32)       // 12 MFMA K-steps
#define VROW 392              // LDS V row stride in bf16 (784 B, 16B-aligned)
#define SCALE 0.8493218002880191f   // sqrt(log2(e)/2); dx'^2 = 0.72134*dx^2

typedef float  f32x4  __attribute__((ext_vector_type(4)));
typedef float  f32x2  __attribute__((ext_vector_type(2)));
typedef __bf16 bf16x8 __attribute__((ext_vector_type(8)));

#if defined(__has_builtin) && __has_builtin(__builtin_amdgcn_exp2f)
#define EXP2F(x) __builtin_amdgcn_exp2f(x)
#else
#define EXP2F(x) __expf((x) * 0.6931471805599453f)
#endif

// V-column order: 0:v1 1:cx*v1 2:cz*v1 | 3..8: v2 {1,cx,cz,ct,cx2,cz2}
// | 9..14: v3 same | 15..20: v4 same
__global__ __launch_bounds__(256) void rbf_fused(
    const float* __restrict__ xp, const float* __restrict__ zp,
    const float* __restrict__ tp, const float* __restrict__ cp,
    const float* __restrict__ v1p, const float* __restrict__ v2p,
    const float* __restrict__ v3p, const float* __restrict__ v4p,
    float* __restrict__ out) {
  __shared__ __align__(16) float  cs[3][KC];       // scaled c slice, 4608 B
  __shared__ __align__(16) __bf16 vlds[21][VROW];  // V slice, 16464 B

  const int rg = blockIdx.x % 96;       // row-group (64 rows)
  const int s  = blockIdx.x / 96;       // K-split 0..15

  // ---- in-block staging from raw inputs (fused prep) ----
  for (int j = threadIdx.x; j < KC; j += 256) {
    const int jg = s * KC + j;
    const float cx = cp[3 * jg], cz = cp[3 * jg + 1], ct = cp[3 * jg + 2];
    cs[0][j] = cx * SCALE; cs[1][j] = cz * SCALE; cs[2][j] = ct * SCALE;
    const float a1 = v1p[jg];
    vlds[0][j] = (__bf16)a1;
    vlds[1][j] = (__bf16)(cx * a1);
    vlds[2][j] = (__bf16)(cz * a1);
    const float vs[3] = {v2p[jg], v3p[jg], v4p[jg]};
#pragma unroll
    for (int k2 = 0; k2 < 3; ++k2) {
      const float v = vs[k2];
      const int r = 3 + 6 * k2;
      vlds[r + 0][j] = (__bf16)v;
      vlds[r + 1][j] = (__bf16)(cx * v);
      vlds[r + 2][j] = (__bf16)(cz * v);
      vlds[r + 3][j] = (__bf16)(ct * v);
      vlds[r + 4][j] = (__bf16)(cx * cx * v);
      vlds[r + 5][j] = (__bf16)(cz * cz * v);
    }
  }
  __syncthreads();

  const int w    = threadIdx.x >> 6;
  const int lane = threadIdx.x & 63;
  const int lo   = lane & 15;           // A row / D col / B col
  const int hi   = lane >> 4;           // k-group: lane holds k = hi*8 + i
  const int lo5  = lo % 5;              // vb1 row (acc1 cols >=5 discarded)

  const int rowbase = rg * 64 + w * 16;
  const int row = rowbase + lo;
  const float xs = xp[row] * SCALE, zs = zp[row] * SCALE, ts = tp[row] * SCALE;
  const f32x2 xs2 = {xs, xs}, zs2 = {zs, zs}, ts2 = {ts, ts};

  f32x4 acc0 = {0.f, 0.f, 0.f, 0.f};
  f32x4 acc1 = {0.f, 0.f, 0.f, 0.f};

#pragma unroll 2
  for (int step = 0; step < NSTEP; ++step) {
    const int kb = hi * 8 + step * 32;
    const f32x2* cxp = (const f32x2*)&cs[0][kb];
    const f32x2* czp = (const f32x2*)&cs[1][kb];
    const f32x2* ctp = (const f32x2*)&cs[2][kb];
    const bf16x8 b0 = *(const bf16x8*)&vlds[lo][kb];         // cols 0..15
    const bf16x8 b1 = *(const bf16x8*)&vlds[16 + lo5][kb];   // cols 16..20

    bf16x8 af;
#pragma unroll
    for (int i = 0; i < 4; ++i) {       // packed fp32: v_pk_fma_f32 path
      const f32x2 dx = cxp[i] - xs2;
      const f32x2 dz = czp[i] - zs2;
      const f32x2 dt = ctp[i] - ts2;
      const f32x2 r2 = __builtin_elementwise_fma(
          dx, dx, __builtin_elementwise_fma(dz, dz, dt * dt));
      af[2 * i]     = (__bf16)EXP2F(-r2.x);   // = exp(-0.5*r2_true)
      af[2 * i + 1] = (__bf16)EXP2F(-r2.y);
    }
    acc0 = __builtin_amdgcn_mfma_f32_16x16x32_bf16(af, b0, acc0, 0, 0, 0);
    acc1 = __builtin_amdgcn_mfma_f32_16x16x32_bf16(af, b1, acc1, 0, 0, 0);
  }

  // ---- W tile -> LDS (reuse staging area), then per-row atomic epilogue ----
  __syncthreads();                       // all waves done reading vlds
  float* redw = reinterpret_cast<float*>(vlds) + w * (16 * 33);
  // D layout: col = lane&15, row = (lane>>4)*4 + reg  [m89-verified]
#pragma unroll
  for (int reg = 0; reg < 4; ++reg) {
    const int r = hi * 4 + reg;
    redw[r * 33 + lo]      = acc0[reg];
    redw[r * 33 + lo + 16] = acc1[reg];
  }
  __syncthreads();

  if (lane < 16) {
    const int orow = rowbase + lane;
    float wv[21];
#pragma unroll
    for (int c = 0; c < 21; ++c) wv[c] = redw[lane * 33 + c];
    const float x = xp[orow], z = zp[orow], t = tp[orow];
    const float x2 = fmaf(x, x, -1.f), z2 = fmaf(z, z, -1.f);
    float* o = out;
    atomicAdd(&o[0 * NPTS + orow],  wv[10] - x * wv[9]);                     // dudx
    atomicAdd(&o[1 * NPTS + orow],  wv[11] - z * wv[9]);                     // dudz
    atomicAdd(&o[2 * NPTS + orow],  wv[12] - t * wv[9]);                     // dudt
    atomicAdd(&o[3 * NPTS + orow],  wv[16] - x * wv[15]);                    // dwdx
    atomicAdd(&o[4 * NPTS + orow],  wv[17] - z * wv[15]);                    // dwdz
    atomicAdd(&o[5 * NPTS + orow],  wv[18] - t * wv[15]);                    // dwdt
    atomicAdd(&o[6 * NPTS + orow],  wv[4]  - x * wv[3]);                     // dbdx
    atomicAdd(&o[7 * NPTS + orow],  wv[5]  - z * wv[3]);                     // dbdz
    atomicAdd(&o[8 * NPTS + orow],  wv[6]  - t * wv[3]);                     // dbdt
    atomicAdd(&o[9 * NPTS + orow],  wv[1]  - x * wv[0]);                     // dpdx
    atomicAdd(&o[10 * NPTS + orow], wv[2]  - z * wv[0]);                     // dpdz
    atomicAdd(&o[11 * NPTS + orow], wv[13] - 2.f * x * wv[10] + x2 * wv[9]); // d2u2x
    atomicAdd(&o[12 * NPTS + orow], wv[14] - 2.f * z * wv[11] + z2 * wv[9]); // d2u2z
    atomicAdd(&o[13 * NPTS + orow], wv[19] - 2.f * x * wv[16] + x2 * wv[15]);// d2w2x
    atomicAdd(&o[14 * NPTS + orow], wv[20] - 2.f * z * wv[17] + z2 * wv[15]);// d2w2z
    atomicAdd(&o[15 * NPTS + orow], wv[7]  - 2.f * x * wv[4]  + x2 * wv[3]); // d2b2x
    atomicAdd(&o[16 * NPTS + orow], wv[8]  - 2.f * z * wv[5]  + z2 * wv[3]); // d2b2z
  }
}

extern "C" void kernel_launch(void* const* d_in, const int* in_sizes, int n_in,
                              void* d_out, int out_size, void* d_ws, size_t ws_size,
                              hipStream_t stream) {
  const float* xp  = (const float*)d_in[0];
  const float* zp  = (const float*)d_in[1];
  const float* tp  = (const float*)d_in[2];
  const float* cp  = (const float*)d_in[3];
  const float* v1p = (const float*)d_in[4];
  const float* v2p = (const float*)d_in[5];
  const float* v3p = (const float*)d_in[6];
  const float* v4p = (const float*)d_in[7];

  // zero d_out (poisoned 0xAA each call; kernel accumulates atomically).
  // Memset nodes are graph-capture legal (harness itself uses hipMemsetAsync).
  hipMemsetAsync(d_out, 0, (size_t)out_size * sizeof(float), stream);

  rbf_fused<<<96 * SPLIT, 256, 0, stream>>>(xp, zp, tp, cp,
                                            v1p, v2p, v3p, v4p, (float*)d_out);
}

// Round 13
// 80.749 us; speedup vs baseline: 1.1867x; 1.0020x over previous
//
#include <hip/hip_runtime.h>
#include <hip/hip_bf16.h>

// RBF collocation, N=6144, 17 outputs (closed-form nested JVPs of Gaussian RBF).
// MFMA factorization (validated R5-R12): out = linear-epilogue( W = G @ V ),
//   G[i,j] = exp(-0.5*||c_j - p_i||^2)  (bf16 A-fragments computed in-lane),
//   V [N x 21] = {v1,cx*v1,cz*v1 | v_k,cx*v_k,cz*v_k,ct*v_k,cx^2*v_k,cz^2*v_k}.
// R13: exponent factoring. G = 2^(-S2|c|^2) * 2^(-S2|p|^2) * 2^(L2E*c.p),
// S2=log2e/2, L2E=log2e. j-factor folded into V at staging (V*=2^-a_j);
// i-factor folded into epilogue (17 outputs *= 2^-b_i); K-loop keeps only the
// bilinear term: 3 pk-ops per j-pair (was 6). Exp/cvt/MFMA counts unchanged.
// Dtypes proven R1-R3: inputs fp32, output fp32. Harness floor ~64us.

#define NPTS 6144
#define SPLIT 16
#define KC (NPTS / SPLIT)     // 384 j per block
#define NSTEP (KC / 32)       // 12 MFMA K-steps
#define VROW 392              // LDS V row stride in bf16 (784 B, 16B-aligned)
#define S2  0.7213475204444817f     // log2(e)/2
#define L2E 1.4426950408889634f     // log2(e)

typedef float  f32x4  __attribute__((ext_vector_type(4)));
typedef float  f32x2  __attribute__((ext_vector_type(2)));
typedef __bf16 bf16x8 __attribute__((ext_vector_type(8)));

#if defined(__has_builtin) && __has_builtin(__builtin_amdgcn_exp2f)
#define EXP2F(x) __builtin_amdgcn_exp2f(x)
#else
#define EXP2F(x) __expf((x) * 0.6931471805599453f)
#endif

// V-column order: 0:v1 1:cx*v1 2:cz*v1 | 3..8: v2 {1,cx,cz,ct,cx2,cz2}
// | 9..14: v3 same | 15..20: v4 same   (all scaled by 2^(-S2*|c_j|^2))
__global__ __launch_bounds__(256) void rbf_fused(
    const float* __restrict__ xp, const float* __restrict__ zp,
    const float* __restrict__ tp, const float* __restrict__ cp,
    const float* __restrict__ v1p, const float* __restrict__ v2p,
    const float* __restrict__ v3p, const float* __restrict__ v4p,
    float* __restrict__ out) {
  __shared__ __align__(16) float  cs[3][KC];       // L2E-scaled c slice
  __shared__ __align__(16) __bf16 vlds[21][VROW];  // V-hat slice, 16464 B

  const int rg = blockIdx.x % 96;       // row-group (64 rows)
  const int s  = blockIdx.x / 96;       // K-split 0..15

  // ---- in-block staging from raw inputs (fused prep) ----
  for (int j = threadIdx.x; j < KC; j += 256) {
    const int jg = s * KC + j;
    const float cx = cp[3 * jg], cz = cp[3 * jg + 1], ct = cp[3 * jg + 2];
    cs[0][j] = cx * L2E; cs[1][j] = cz * L2E; cs[2][j] = ct * L2E;
    // fold 2^(-S2*|c|^2) into the V row
    const float aj  = S2 * fmaf(cx, cx, fmaf(cz, cz, ct * ct));
    const float e2a = EXP2F(-aj);
    const float a1 = v1p[jg] * e2a;
    vlds[0][j] = (__bf16)a1;
    vlds[1][j] = (__bf16)(cx * a1);
    vlds[2][j] = (__bf16)(cz * a1);
    const float vs[3] = {v2p[jg] * e2a, v3p[jg] * e2a, v4p[jg] * e2a};
#pragma unroll
    for (int k2 = 0; k2 < 3; ++k2) {
      const float v = vs[k2];
      const int r = 3 + 6 * k2;
      vlds[r + 0][j] = (__bf16)v;
      vlds[r + 1][j] = (__bf16)(cx * v);
      vlds[r + 2][j] = (__bf16)(cz * v);
      vlds[r + 3][j] = (__bf16)(ct * v);
      vlds[r + 4][j] = (__bf16)(cx * cx * v);
      vlds[r + 5][j] = (__bf16)(cz * cz * v);
    }
  }
  __syncthreads();

  const int w    = threadIdx.x >> 6;
  const int lane = threadIdx.x & 63;
  const int lo   = lane & 15;           // A row / D col / B col
  const int hi   = lane >> 4;           // k-group: lane holds k = hi*8 + i
  const int lo5  = lo % 5;              // vb1 row (acc1 cols >=5 discarded)

  const int rowbase = rg * 64 + w * 16;
  const int row = rowbase + lo;
  const float xi = xp[row], zi = zp[row], ti = tp[row];
  const f32x2 xs2 = {xi, xi}, zs2 = {zi, zi}, ts2 = {ti, ti};

  f32x4 acc0 = {0.f, 0.f, 0.f, 0.f};
  f32x4 acc1 = {0.f, 0.f, 0.f, 0.f};

#pragma unroll 2
  for (int step = 0; step < NSTEP; ++step) {
    const int kb = hi * 8 + step * 32;
    const f32x2* cxp = (const f32x2*)&cs[0][kb];
    const f32x2* czp = (const f32x2*)&cs[1][kb];
    const f32x2* ctp = (const f32x2*)&cs[2][kb];
    const bf16x8 b0 = *(const bf16x8*)&vlds[lo][kb];         // cols 0..15
    const bf16x8 b1 = *(const bf16x8*)&vlds[16 + lo5][kb];   // cols 16..20

    bf16x8 af;
#pragma unroll
    for (int i = 0; i < 4; ++i) {       // bilinear term only: 3 pk-ops / pair
      const f32x2 d = __builtin_elementwise_fma(
          cxp[i], xs2,
          __builtin_elementwise_fma(czp[i], zs2, ctp[i] * ts2));
      af[2 * i]     = (__bf16)EXP2F(d.x);   // G-hat = 2^(L2E*c.p)
      af[2 * i + 1] = (__bf16)EXP2F(d.y);
    }
    acc0 = __builtin_amdgcn_mfma_f32_16x16x32_bf16(af, b0, acc0, 0, 0, 0);
    acc1 = __builtin_amdgcn_mfma_f32_16x16x32_bf16(af, b1, acc1, 0, 0, 0);
  }

  // ---- W tile -> LDS (reuse staging area), then per-row atomic epilogue ----
  __syncthreads();                       // all waves done reading vlds
  float* redw = reinterpret_cast<float*>(vlds) + w * (16 * 33);
  // D layout: col = lane&15, row = (lane>>4)*4 + reg  [m89-verified]
#pragma unroll
  for (int reg = 0; reg < 4; ++reg) {
    const int r = hi * 4 + reg;
    redw[r * 33 + lo]      = acc0[reg];
    redw[r * 33 + lo + 16] = acc1[reg];
  }
  __syncthreads();

  if (lane < 16) {
    const int orow = rowbase + lane;
    float wv[21];
#pragma unroll
    for (int c = 0; c < 21; ++c) wv[c] = redw[lane * 33 + c];
    const float x = xp[orow], z = zp[orow], t = tp[orow];
    // fold 2^(-S2*|p|^2) here (outputs are linear in W)
    const float gi = EXP2F(-S2 * fmaf(x, x, fmaf(z, z, t * t)));
    const float x2 = fmaf(x, x, -1.f), z2 = fmaf(z, z, -1.f);
    float* o = out;
    atomicAdd(&o[0 * NPTS + orow],  gi * (wv[10] - x * wv[9]));                     // dudx
    atomicAdd(&o[1 * NPTS + orow],  gi * (wv[11] - z * wv[9]));                     // dudz
    atomicAdd(&o[2 * NPTS + orow],  gi * (wv[12] - t * wv[9]));                     // dudt
    atomicAdd(&o[3 * NPTS + orow],  gi * (wv[16] - x * wv[15]));                    // dwdx
    atomicAdd(&o[4 * NPTS + orow],  gi * (wv[17] - z * wv[15]));                    // dwdz
    atomicAdd(&o[5 * NPTS + orow],  gi * (wv[18] - t * wv[15]));                    // dwdt
    atomicAdd(&o[6 * NPTS + orow],  gi * (wv[4]  - x * wv[3]));                     // dbdx
    atomicAdd(&o[7 * NPTS + orow],  gi * (wv[5]  - z * wv[3]));                     // dbdz
    atomicAdd(&o[8 * NPTS + orow],  gi * (wv[6]  - t * wv[3]));                     // dbdt
    atomicAdd(&o[9 * NPTS + orow],  gi * (wv[1]  - x * wv[0]));                     // dpdx
    atomicAdd(&o[10 * NPTS + orow], gi * (wv[2]  - z * wv[0]));                     // dpdz
    atomicAdd(&o[11 * NPTS + orow], gi * (wv[13] - 2.f * x * wv[10] + x2 * wv[9])); // d2u2x
    atomicAdd(&o[12 * NPTS + orow], gi * (wv[14] - 2.f * z * wv[11] + z2 * wv[9])); // d2u2z
    atomicAdd(&o[13 * NPTS + orow], gi * (wv[19] - 2.f * x * wv[16] + x2 * wv[15]));// d2w2x
    atomicAdd(&o[14 * NPTS + orow], gi * (wv[20] - 2.f * z * wv[17] + z2 * wv[15]));// d2w2z
    atomicAdd(&o[15 * NPTS + orow], gi * (wv[7]  - 2.f * x * wv[4]  + x2 * wv[3])); // d2b2x
    atomicAdd(&o[16 * NPTS + orow], gi * (wv[8]  - 2.f * z * wv[5]  + z2 * wv[3])); // d2b2z
  }
}

extern "C" void kernel_launch(void* const* d_in, const int* in_sizes, int n_in,
                              void* d_out, int out_size, void* d_ws, size_t ws_size,
                              hipStream_t stream) {
  const float* xp  = (const float*)d_in[0];
  const float* zp  = (const float*)d_in[1];
  const float* tp  = (const float*)d_in[2];
  const float* cp  = (const float*)d_in[3];
  const float* v1p = (const float*)d_in[4];
  const float* v2p = (const float*)d_in[5];
  const float* v3p = (const float*)d_in[6];
  const float* v4p = (const float*)d_in[7];

  // zero d_out (poisoned 0xAA each call; kernel accumulates atomically).
  hipMemsetAsync(d_out, 0, (size_t)out_size * sizeof(float), stream);

  rbf_fused<<<96 * SPLIT, 256, 0, stream>>>(xp, zp, tp, cp,
                                            v1p, v2p, v3p, v4p, (float*)d_out);
}